// Round 5
// baseline (689.050 us; speedup 1.0000x reference)
//
#include <hip/hip_runtime.h>
#include <math.h>
#include <type_traits>

#define NNODES 100000
#define NEDGES 1600000
#define NGRAPH 128

typedef _Float16 f16x4 __attribute__((ext_vector_type(4)));
typedef _Float16 f16x8 __attribute__((ext_vector_type(8)));
typedef float f32x4 __attribute__((ext_vector_type(4)));

// ---------------- MFMA GEMM: C[M,N] = A[M,K] * B[N,K]^T, fp16 in, fp16 out ------
template <int K, int N, typename AT>
__global__ __launch_bounds__(256) void gemm_mfma(const AT* __restrict__ A,
    const float* __restrict__ B, _Float16* __restrict__ C, int M) {
  constexpr int BM = 128;
  __shared__ _Float16 As[BM * K];
  __shared__ _Float16 Bs[N * K];
  const int tid = threadIdx.x;
  const int bm = blockIdx.x * BM;

  for (int i = tid * 4; i < BM * K; i += 1024) {
    int row = i / K;
    int k = i & (K - 1);
    int gr = bm + row;
    f16x4 h;
    if constexpr (std::is_same<AT, float>::value) {
      float4 v = {0.f, 0.f, 0.f, 0.f};
      if (gr < M) v = *(const float4*)&A[(size_t)gr * K + k];
      h[0] = (_Float16)v.x; h[1] = (_Float16)v.y; h[2] = (_Float16)v.z; h[3] = (_Float16)v.w;
    } else {
      f16x4 v = {};
      if (gr < M) v = *(const f16x4*)&A[(size_t)gr * K + k];
      h = v;
    }
    int idx = (row * K + k) ^ ((row & 7) << 3);
    *(f16x4*)&As[idx] = h;
  }
  for (int i = tid * 4; i < N * K; i += 1024) {
    int row = i / K;
    int k = i & (K - 1);
    float4 v = *(const float4*)&B[(size_t)row * K + k];
    f16x4 h;
    h[0] = (_Float16)v.x; h[1] = (_Float16)v.y; h[2] = (_Float16)v.z; h[3] = (_Float16)v.w;
    int idx = (row * K + k) ^ ((row & 7) << 3);
    *(f16x4*)&Bs[idx] = h;
  }
  __syncthreads();

  const int lane = tid & 63, wid = tid >> 6;
  const int lr = lane & 15;
  const int lk = (lane >> 4) * 8;
  constexpr int KS = K / 32, NT = N / 16;

  f16x8 a[2][KS];
#pragma unroll
  for (int mf = 0; mf < 2; ++mf)
#pragma unroll
    for (int ks = 0; ks < KS; ++ks) {
      int row = wid * 32 + mf * 16 + lr;
      int idx = (row * K + ks * 32 + lk) ^ ((row & 7) << 3);
      a[mf][ks] = *(const f16x8*)&As[idx];
    }

  f32x4 acc[2][NT];
#pragma unroll
  for (int mf = 0; mf < 2; ++mf)
#pragma unroll
    for (int nt = 0; nt < NT; ++nt) acc[mf][nt] = (f32x4){0.f, 0.f, 0.f, 0.f};

#pragma unroll
  for (int nt = 0; nt < NT; ++nt)
#pragma unroll
    for (int ks = 0; ks < KS; ++ks) {
      int row = nt * 16 + lr;
      int idx = (row * K + ks * 32 + lk) ^ ((row & 7) << 3);
      f16x8 b = *(const f16x8*)&Bs[idx];
      acc[0][nt] = __builtin_amdgcn_mfma_f32_16x16x32_f16(a[0][ks], b, acc[0][nt], 0, 0, 0);
      acc[1][nt] = __builtin_amdgcn_mfma_f32_16x16x32_f16(a[1][ks], b, acc[1][nt], 0, 0, 0);
    }

#pragma unroll
  for (int mf = 0; mf < 2; ++mf) {
    int row0 = bm + wid * 32 + mf * 16 + (lane >> 4) * 4;
#pragma unroll
    for (int nt = 0; nt < NT; ++nt)
#pragma unroll
      for (int r = 0; r < 4; ++r) {
        int row = row0 + r;
        if (row < M) C[(size_t)row * N + nt * 16 + lr] = (_Float16)acc[mf][nt][r];
      }
  }
}

// ---------------- per-node attention logits ----------------
template <int H>
__global__ void alpha_kernel(const _Float16* __restrict__ hmat,
                             const float* __restrict__ a_src, const float* __restrict__ a_dst,
                             float* __restrict__ asrc, float* __restrict__ adst, int n) {
  int lane = threadIdx.x & 63;
  int node = blockIdx.x * 4 + (threadIdx.x >> 6);
  if (node >= n) return;
#pragma unroll
  for (int h = 0; h < H; ++h) {
    float v = (float)hmat[(size_t)node * (H * 64) + h * 64 + lane];
    float ps = v * a_src[h * 64 + lane];
    float pd = v * a_dst[h * 64 + lane];
#pragma unroll
    for (int o = 32; o; o >>= 1) { ps += __shfl_xor(ps, o); pd += __shfl_xor(pd, o); }
    if (lane == 0) { asrc[node * H + h] = ps; adst[node * H + h] = pd; }
  }
}

// ---------------- CSR build ----------------
__global__ void hist_kernel(const int* __restrict__ dstv, int* __restrict__ deg, int e_count) {
  int e = blockIdx.x * blockDim.x + threadIdx.x;
  if (e < e_count) atomicAdd(&deg[dstv[e]], 1);
}

__global__ __launch_bounds__(1024) void scan1(const int* __restrict__ deg, int* __restrict__ inc,
                                              int* __restrict__ bsum, int n) {
  __shared__ int sm[1024];
  int i = blockIdx.x * 1024 + threadIdx.x;
  sm[threadIdx.x] = (i < n) ? deg[i] : 0;
  __syncthreads();
  for (int o = 1; o < 1024; o <<= 1) {
    int t = (threadIdx.x >= o) ? sm[threadIdx.x - o] : 0;
    __syncthreads();
    sm[threadIdx.x] += t;
    __syncthreads();
  }
  if (i < n) inc[i] = sm[threadIdx.x];
  if (threadIdx.x == 1023) bsum[blockIdx.x] = sm[1023];
}

__global__ void scan2(const int* __restrict__ bsum, int* __restrict__ boff, int nb) {
  __shared__ int sm[128];
  int t = threadIdx.x;
  int own = (t < nb) ? bsum[t] : 0;
  sm[t] = own;
  __syncthreads();
  for (int o = 1; o < 128; o <<= 1) {
    int u = (t >= o) ? sm[t - o] : 0;
    __syncthreads();
    sm[t] += u;
    __syncthreads();
  }
  if (t < nb) boff[t] = sm[t] - own;
}

__global__ void scan3(const int* __restrict__ inc, const int* __restrict__ deg,
                      const int* __restrict__ boff, int* __restrict__ offsets, int n, int e_count) {
  int i = blockIdx.x * blockDim.x + threadIdx.x;
  if (i < n) offsets[i] = inc[i] - deg[i] + boff[i >> 10];
  if (i == 0) offsets[n] = e_count;
}

__global__ void scatter_kernel(const int* __restrict__ srcv, const int* __restrict__ dstv,
                               int* __restrict__ cursor, int* __restrict__ esrc, int e_count) {
  int e = blockIdx.x * blockDim.x + threadIdx.x;
  if (e < e_count) {
    int p = atomicAdd(&cursor[dstv[e]], 1);
    esrc[p] = srcv[e];
  }
}

// ------------- layer-1 aggregation: one wave-load = one full 512B h-row ---------
// Block 256 = 4 waves, one node per block. Lane l owns channels l*4..l*4+3
// (head = l>>4). Waves split edges stride-4; LDS reduce at end.
template <int CH>
__global__ __launch_bounds__(256) void agg1_kernel(const _Float16* __restrict__ hmat,
    const float* __restrict__ asrc, const float* __restrict__ adst,
    const int* __restrict__ offsets, const int* __restrict__ esrc,
    const float* __restrict__ bias, _Float16* __restrict__ outv) {
  const int node = blockIdx.x;
  const int tid = threadIdx.x;
  const int lane = tid & 63, wid = tid >> 6;
  const int h = lane >> 4;
  const int start = offsets[node];
  const int deg = offsets[node + 1] - start;
  __shared__ float pvT[4][CH + 8];   // +8 pad: per-head rows land in distinct banks
  __shared__ int soff[CH];
  __shared__ float redA[4][64][4];
  __shared__ float redS[4][64];
  float acc[4] = {0.f, 0.f, 0.f, 0.f};
  float s = 0.f;
  const _Float16* hbase = hmat + lane * 4;
  for (int base = 0; base < deg; base += CH) {
    const int cn = min(CH, deg - base);
    __syncthreads();
    if (tid < cn) {
      int sv = esrc[start + base + tid];
      soff[tid] = sv * 256;
#pragma unroll
      for (int hh = 0; hh < 4; ++hh) {
        float v = asrc[sv * 4 + hh] + adst[node * 4 + hh];
        v = (v > 0.f) ? v : 0.2f * v;
        pvT[hh][tid] = __expf(v);
      }
    }
    __syncthreads();
    int j = wid;
    for (; j + 12 < cn; j += 16) {
      float p0 = pvT[h][j], p1 = pvT[h][j + 4], p2 = pvT[h][j + 8], p3 = pvT[h][j + 12];
      int o0 = soff[j], o1 = soff[j + 4], o2 = soff[j + 8], o3 = soff[j + 12];
      f16x4 v0 = *(const f16x4*)&hbase[o0];
      f16x4 v1 = *(const f16x4*)&hbase[o1];
      f16x4 v2 = *(const f16x4*)&hbase[o2];
      f16x4 v3 = *(const f16x4*)&hbase[o3];
      s += (p0 + p1) + (p2 + p3);
#pragma unroll
      for (int k = 0; k < 4; ++k) {
        acc[k] = fmaf(p0, (float)v0[k], acc[k]);
        acc[k] = fmaf(p1, (float)v1[k], acc[k]);
        acc[k] = fmaf(p2, (float)v2[k], acc[k]);
        acc[k] = fmaf(p3, (float)v3[k], acc[k]);
      }
    }
    for (; j < cn; j += 4) {
      float p = pvT[h][j];
      f16x4 v = *(const f16x4*)&hbase[soff[j]];
      s += p;
#pragma unroll
      for (int k = 0; k < 4; ++k) acc[k] = fmaf(p, (float)v[k], acc[k]);
    }
  }
#pragma unroll
  for (int k = 0; k < 4; ++k) redA[wid][lane][k] = acc[k];
  redS[wid][lane] = s;
  __syncthreads();
  if (tid < 64) {
    float a[4];
#pragma unroll
    for (int k = 0; k < 4; ++k)
      a[k] = (redA[0][tid][k] + redA[1][tid][k]) + (redA[2][tid][k] + redA[3][tid][k]);
    float st = ((redS[0][tid] + redS[1][tid]) + (redS[2][tid] + redS[3][tid])) + 1e-16f;
    f16x4 ho;
#pragma unroll
    for (int k = 0; k < 4; ++k) {
      float o = a[k] / st + bias[tid * 4 + k];
      ho[k] = (_Float16)fmaxf(o, 0.f);
    }
    *(f16x4*)&outv[(size_t)node * 256 + tid * 4] = ho;
  }
}

// ------------- layer-2 aggregation: 16 lanes per edge, 4 edges per wave-load ----
template <int CH>
__global__ __launch_bounds__(256) void agg2_kernel(const _Float16* __restrict__ hmat,
    const float* __restrict__ asrc, const float* __restrict__ adst,
    const int* __restrict__ offsets, const int* __restrict__ esrc,
    const float* __restrict__ bias, float* __restrict__ outv) {
  const int node = blockIdx.x;
  const int tid = threadIdx.x;
  const int lane = tid & 63, wid = tid >> 6;
  const int g = lane >> 4, q = lane & 15;
  const int start = offsets[node];
  const int deg = offsets[node + 1] - start;
  __shared__ float pv[CH];
  __shared__ int soff[CH];
  __shared__ float redA[4][16][4];
  __shared__ float redS[4][16];
  float acc[4] = {0.f, 0.f, 0.f, 0.f};
  float s = 0.f;
  const _Float16* hbase = hmat + q * 4;
  const float adn = adst[node];
  for (int base = 0; base < deg; base += CH) {
    const int cn = min(CH, deg - base);
    __syncthreads();
    if (tid < cn) {
      int sv = esrc[start + base + tid];
      soff[tid] = sv * 64;
      float v = asrc[sv] + adn;
      v = (v > 0.f) ? v : 0.2f * v;
      pv[tid] = __expf(v);
    }
    __syncthreads();
    int j = wid * 4 + g;
    for (; j + 16 < cn; j += 32) {
      float p0 = pv[j], p1 = pv[j + 16];
      int o0 = soff[j], o1 = soff[j + 16];
      f16x4 v0 = *(const f16x4*)&hbase[o0];
      f16x4 v1 = *(const f16x4*)&hbase[o1];
      s += p0 + p1;
#pragma unroll
      for (int k = 0; k < 4; ++k) {
        acc[k] = fmaf(p0, (float)v0[k], acc[k]);
        acc[k] = fmaf(p1, (float)v1[k], acc[k]);
      }
    }
    for (; j < cn; j += 16) {
      float p = pv[j];
      f16x4 v = *(const f16x4*)&hbase[soff[j]];
      s += p;
#pragma unroll
      for (int k = 0; k < 4; ++k) acc[k] = fmaf(p, (float)v[k], acc[k]);
    }
  }
#pragma unroll
  for (int k = 0; k < 4; ++k) {
    acc[k] += __shfl_xor(acc[k], 16);
    acc[k] += __shfl_xor(acc[k], 32);
  }
  s += __shfl_xor(s, 16);
  s += __shfl_xor(s, 32);
  if (lane < 16) {
#pragma unroll
    for (int k = 0; k < 4; ++k) redA[wid][lane][k] = acc[k];
    redS[wid][lane] = s;
  }
  __syncthreads();
  if (tid < 16) {
    float a[4];
#pragma unroll
    for (int k = 0; k < 4; ++k)
      a[k] = (redA[0][tid][k] + redA[1][tid][k]) + (redA[2][tid][k] + redA[3][tid][k]);
    float st = ((redS[0][tid] + redS[1][tid]) + (redS[2][tid] + redS[3][tid])) + 1e-16f;
    float4 o;
    o.x = fmaxf(a[0] / st + bias[tid * 4 + 0], 0.f);
    o.y = fmaxf(a[1] / st + bias[tid * 4 + 1], 0.f);
    o.z = fmaxf(a[2] / st + bias[tid * 4 + 2], 0.f);
    o.w = fmaxf(a[3] / st + bias[tid * 4 + 3], 0.f);
    *(float4*)&outv[(size_t)node * 64 + tid * 4] = o;
  }
}

// ---------------- global mean pool ----------------
__global__ void graph_count_kernel(const int* __restrict__ batch, int* __restrict__ cnt, int n) {
  int g = threadIdx.x;
  if (g >= NGRAPH) return;
  int lo = 0, hi = n;
  while (lo < hi) { int mid = (lo + hi) >> 1; if (batch[mid] < g) lo = mid + 1; else hi = mid; }
  int lb = lo;
  hi = n;
  while (lo < hi) { int mid = (lo + hi) >> 1; if (batch[mid] < g + 1) lo = mid + 1; else hi = mid; }
  cnt[g] = lo - lb;
}

__global__ void pool_sum_kernel(const float* __restrict__ g2, const int* __restrict__ batch,
                                float* __restrict__ sums, int n) {
  int c = threadIdx.x;  // 64
  int beg = blockIdx.x * 64;
  int end = min(beg + 64, n);
  if (beg >= n) return;
  int cur = batch[beg];
  float acc = 0.f;
  for (int i = beg; i < end; ++i) {
    int g = batch[i];
    if (g != cur) {
      atomicAdd(&sums[cur * 64 + c], acc);
      acc = 0.f;
      cur = g;
    }
    acc += g2[(size_t)i * 64 + c];
  }
  atomicAdd(&sums[cur * 64 + c], acc);
}

__global__ void pool_div_kernel(const float* __restrict__ sums, const int* __restrict__ cnt,
                                float* __restrict__ out) {
  int i = blockIdx.x * blockDim.x + threadIdx.x;
  if (i < NGRAPH * 64) out[i] = sums[i] / fmaxf((float)cnt[i >> 6], 1.f);
}

// ---------------- launcher ----------------
extern "C" void kernel_launch(void* const* d_in, const int* in_sizes, int n_in,
                              void* d_out, int out_size, void* d_ws, size_t ws_size,
                              hipStream_t stream) {
  const float* x      = (const float*)d_in[0];
  const float* w1     = (const float*)d_in[1];
  const float* a_src1 = (const float*)d_in[2];
  const float* a_dst1 = (const float*)d_in[3];
  const float* b1     = (const float*)d_in[4];
  const float* w2     = (const float*)d_in[5];
  const float* a_src2 = (const float*)d_in[6];
  const float* a_dst2 = (const float*)d_in[7];
  const float* b2     = (const float*)d_in[8];
  const int*   src    = (const int*)d_in[9];
  const int*   dst    = src + NEDGES;
  const int*   batch  = (const int*)d_in[10];
  float* out = (float*)d_out;

  const int N = NNODES, E = NEDGES;
  const int NB = (N + 1023) / 1024;

  char* wsb = (char*)d_ws;
  size_t off = 0;
  auto alloc = [&](size_t bytes) {
    void* p = wsb + off;
    off = (off + bytes + 255) & ~(size_t)255;
    return p;
  };
  _Float16* h1h = (_Float16*)alloc((size_t)N * 256 * 2);
  _Float16* g1h = (_Float16*)alloc((size_t)N * 256 * 2);
  _Float16* h2h = (_Float16*)alloc((size_t)N * 64 * 2);
  float* g2     = (float*)alloc((size_t)N * 64 * 4);
  float* as1    = (float*)alloc((size_t)N * 4 * 4);
  float* ad1    = (float*)alloc((size_t)N * 4 * 4);
  float* as2    = (float*)alloc((size_t)N * 4);
  float* ad2    = (float*)alloc((size_t)N * 4);
  int* deg      = (int*)alloc((size_t)N * 4);
  int* inc      = (int*)alloc((size_t)N * 4);
  int* bsum     = (int*)alloc((size_t)NB * 4);
  int* boff     = (int*)alloc((size_t)NB * 4);
  int* offsets  = (int*)alloc((size_t)(N + 1) * 4);
  int* cursor   = (int*)alloc((size_t)N * 4);
  int* esrc     = (int*)alloc((size_t)E * 4);
  float* sums   = (float*)alloc((size_t)NGRAPH * 64 * 4);
  int* cnt      = (int*)alloc((size_t)NGRAPH * 4);

  // ---- CSR build ----
  hipMemsetAsync(deg, 0, (size_t)N * 4, stream);
  hist_kernel<<<(E + 255) / 256, 256, 0, stream>>>(dst, deg, E);
  scan1<<<NB, 1024, 0, stream>>>(deg, inc, bsum, N);
  scan2<<<1, 128, 0, stream>>>(bsum, boff, NB);
  scan3<<<(N + 255) / 256, 256, 0, stream>>>(inc, deg, boff, offsets, N, E);
  hipMemcpyAsync(cursor, offsets, (size_t)N * 4, hipMemcpyDeviceToDevice, stream);
  scatter_kernel<<<(E + 255) / 256, 256, 0, stream>>>(src, dst, cursor, esrc, E);

  // ---- layer 1 ----
  gemm_mfma<128, 256, float><<<(N + 127) / 128, 256, 0, stream>>>(x, w1, h1h, N);
  alpha_kernel<4><<<(N + 3) / 4, 256, 0, stream>>>(h1h, a_src1, a_dst1, as1, ad1, N);
  agg1_kernel<64><<<N, 256, 0, stream>>>(h1h, as1, ad1, offsets, esrc, b1, g1h);

  // ---- layer 2 ----
  gemm_mfma<256, 64, _Float16><<<(N + 127) / 128, 256, 0, stream>>>(g1h, w2, h2h, N);
  alpha_kernel<1><<<(N + 3) / 4, 256, 0, stream>>>(h2h, a_src2, a_dst2, as2, ad2, N);
  agg2_kernel<64><<<N, 256, 0, stream>>>(h2h, as2, ad2, offsets, esrc, b2, g2);

  // ---- pool ----
  hipMemsetAsync(sums, 0, (size_t)NGRAPH * 64 * 4, stream);
  graph_count_kernel<<<1, 128, 0, stream>>>(batch, cnt, N);
  pool_sum_kernel<<<(N + 63) / 64, 64, 0, stream>>>(g2, batch, sums, N);
  pool_div_kernel<<<(NGRAPH * 64 + 255) / 256, 256, 0, stream>>>(sums, cnt, out);
}

// Round 6
// 626.098 us; speedup vs baseline: 1.1005x; 1.1005x over previous
//
#include <hip/hip_runtime.h>
#include <math.h>
#include <type_traits>

#define NNODES 100000
#define NEDGES 1600000
#define NGRAPH 128

typedef _Float16 f16x4 __attribute__((ext_vector_type(4)));
typedef _Float16 f16x8 __attribute__((ext_vector_type(8)));
typedef float f32x4 __attribute__((ext_vector_type(4)));

// ---------------- MFMA GEMM: C[M,N] = A[M,K] * B[N,K]^T, fp16 in, fp16 out ------
template <int K, int N, typename AT>
__global__ __launch_bounds__(256) void gemm_mfma(const AT* __restrict__ A,
    const float* __restrict__ B, _Float16* __restrict__ C, int M) {
  constexpr int BM = 128;
  __shared__ _Float16 As[BM * K];
  __shared__ _Float16 Bs[N * K];
  const int tid = threadIdx.x;
  const int bm = blockIdx.x * BM;

  for (int i = tid * 4; i < BM * K; i += 1024) {
    int row = i / K;
    int k = i & (K - 1);
    int gr = bm + row;
    f16x4 h;
    if constexpr (std::is_same<AT, float>::value) {
      float4 v = {0.f, 0.f, 0.f, 0.f};
      if (gr < M) v = *(const float4*)&A[(size_t)gr * K + k];
      h[0] = (_Float16)v.x; h[1] = (_Float16)v.y; h[2] = (_Float16)v.z; h[3] = (_Float16)v.w;
    } else {
      f16x4 v = {};
      if (gr < M) v = *(const f16x4*)&A[(size_t)gr * K + k];
      h = v;
    }
    int idx = (row * K + k) ^ ((row & 7) << 3);
    *(f16x4*)&As[idx] = h;
  }
  for (int i = tid * 4; i < N * K; i += 1024) {
    int row = i / K;
    int k = i & (K - 1);
    float4 v = *(const float4*)&B[(size_t)row * K + k];
    f16x4 h;
    h[0] = (_Float16)v.x; h[1] = (_Float16)v.y; h[2] = (_Float16)v.z; h[3] = (_Float16)v.w;
    int idx = (row * K + k) ^ ((row & 7) << 3);
    *(f16x4*)&Bs[idx] = h;
  }
  __syncthreads();

  const int lane = tid & 63, wid = tid >> 6;
  const int lr = lane & 15;
  const int lk = (lane >> 4) * 8;
  constexpr int KS = K / 32, NT = N / 16;

  f16x8 a[2][KS];
#pragma unroll
  for (int mf = 0; mf < 2; ++mf)
#pragma unroll
    for (int ks = 0; ks < KS; ++ks) {
      int row = wid * 32 + mf * 16 + lr;
      int idx = (row * K + ks * 32 + lk) ^ ((row & 7) << 3);
      a[mf][ks] = *(const f16x8*)&As[idx];
    }

  f32x4 acc[2][NT];
#pragma unroll
  for (int mf = 0; mf < 2; ++mf)
#pragma unroll
    for (int nt = 0; nt < NT; ++nt) acc[mf][nt] = (f32x4){0.f, 0.f, 0.f, 0.f};

#pragma unroll
  for (int nt = 0; nt < NT; ++nt)
#pragma unroll
    for (int ks = 0; ks < KS; ++ks) {
      int row = nt * 16 + lr;
      int idx = (row * K + ks * 32 + lk) ^ ((row & 7) << 3);
      f16x8 b = *(const f16x8*)&Bs[idx];
      acc[0][nt] = __builtin_amdgcn_mfma_f32_16x16x32_f16(a[0][ks], b, acc[0][nt], 0, 0, 0);
      acc[1][nt] = __builtin_amdgcn_mfma_f32_16x16x32_f16(a[1][ks], b, acc[1][nt], 0, 0, 0);
    }

#pragma unroll
  for (int mf = 0; mf < 2; ++mf) {
    int row0 = bm + wid * 32 + mf * 16 + (lane >> 4) * 4;
#pragma unroll
    for (int nt = 0; nt < NT; ++nt)
#pragma unroll
      for (int r = 0; r < 4; ++r) {
        int row = row0 + r;
        if (row < M) C[(size_t)row * N + nt * 16 + lr] = (_Float16)acc[mf][nt][r];
      }
  }
}

// ---------------- per-node attention logits ----------------
template <int H>
__global__ void alpha_kernel(const _Float16* __restrict__ hmat,
                             const float* __restrict__ a_src, const float* __restrict__ a_dst,
                             float* __restrict__ asrc, float* __restrict__ adst, int n) {
  int lane = threadIdx.x & 63;
  int node = blockIdx.x * 4 + (threadIdx.x >> 6);
  if (node >= n) return;
#pragma unroll
  for (int h = 0; h < H; ++h) {
    float v = (float)hmat[(size_t)node * (H * 64) + h * 64 + lane];
    float ps = v * a_src[h * 64 + lane];
    float pd = v * a_dst[h * 64 + lane];
#pragma unroll
    for (int o = 32; o; o >>= 1) { ps += __shfl_xor(ps, o); pd += __shfl_xor(pd, o); }
    if (lane == 0) { asrc[node * H + h] = ps; adst[node * H + h] = pd; }
  }
}

// ---------------- CSR build ----------------
__global__ void hist_kernel(const int* __restrict__ dstv, int* __restrict__ deg, int e_count) {
  int e = blockIdx.x * blockDim.x + threadIdx.x;
  if (e < e_count) atomicAdd(&deg[dstv[e]], 1);
}

__global__ __launch_bounds__(1024) void scan1(const int* __restrict__ deg, int* __restrict__ inc,
                                              int* __restrict__ bsum, int n) {
  __shared__ int sm[1024];
  int i = blockIdx.x * 1024 + threadIdx.x;
  sm[threadIdx.x] = (i < n) ? deg[i] : 0;
  __syncthreads();
  for (int o = 1; o < 1024; o <<= 1) {
    int t = (threadIdx.x >= o) ? sm[threadIdx.x - o] : 0;
    __syncthreads();
    sm[threadIdx.x] += t;
    __syncthreads();
  }
  if (i < n) inc[i] = sm[threadIdx.x];
  if (threadIdx.x == 1023) bsum[blockIdx.x] = sm[1023];
}

__global__ void scan2(const int* __restrict__ bsum, int* __restrict__ boff, int nb) {
  __shared__ int sm[128];
  int t = threadIdx.x;
  int own = (t < nb) ? bsum[t] : 0;
  sm[t] = own;
  __syncthreads();
  for (int o = 1; o < 128; o <<= 1) {
    int u = (t >= o) ? sm[t - o] : 0;
    __syncthreads();
    sm[t] += u;
    __syncthreads();
  }
  if (t < nb) boff[t] = sm[t] - own;
}

__global__ void scan3(const int* __restrict__ inc, const int* __restrict__ deg,
                      const int* __restrict__ boff, int* __restrict__ offsets, int n, int e_count) {
  int i = blockIdx.x * blockDim.x + threadIdx.x;
  if (i < n) offsets[i] = inc[i] - deg[i] + boff[i >> 10];
  if (i == 0) offsets[n] = e_count;
}

__global__ void scatter_kernel(const int* __restrict__ srcv, const int* __restrict__ dstv,
                               int* __restrict__ cursor, int* __restrict__ esrc, int e_count) {
  int e = blockIdx.x * blockDim.x + threadIdx.x;
  if (e < e_count) {
    int p = atomicAdd(&cursor[dstv[e]], 1);
    esrc[p] = srcv[e];
  }
}

// ------------- layer-1 aggregation: one WAVE per node, no LDS, no barriers ------
// Lane owns channels lane*4..lane*4+3 (head = lane>>4). One 512B row-gather per
// edge per wave; unroll x8 keeps 8 gathers in flight.
__global__ __launch_bounds__(256) void agg1_kernel(const _Float16* __restrict__ hmat,
    const float* __restrict__ asrc, const float* __restrict__ adst,
    const int* __restrict__ offsets, const int* __restrict__ esrc,
    const float* __restrict__ bias, _Float16* __restrict__ outv) {
  const int lane = threadIdx.x & 63, wid = threadIdx.x >> 6;
  const int node = blockIdx.x * 4 + wid;
  if (node >= NNODES) return;
  const int h = lane >> 4;
  const int start = offsets[node];
  const int end = offsets[node + 1];
  const float adn = adst[node * 4 + h];
  const _Float16* hbase = hmat + lane * 4;
  float acc[4] = {0.f, 0.f, 0.f, 0.f};
  float s = 0.f;
  int j = start;
  for (; j + 8 <= end; j += 8) {
    int sv[8];
#pragma unroll
    for (int t = 0; t < 8; ++t) sv[t] = esrc[j + t];
    f16x4 vv[8];
#pragma unroll
    for (int t = 0; t < 8; ++t) vv[t] = *(const f16x4*)&hbase[(size_t)sv[t] * 256];
    float p[8];
#pragma unroll
    for (int t = 0; t < 8; ++t) {
      float v = asrc[sv[t] * 4 + h] + adn;
      v = (v > 0.f) ? v : 0.2f * v;
      p[t] = __expf(v);
    }
#pragma unroll
    for (int t = 0; t < 8; ++t) {
      s += p[t];
#pragma unroll
      for (int k = 0; k < 4; ++k) acc[k] = fmaf(p[t], (float)vv[t][k], acc[k]);
    }
  }
  for (; j < end; ++j) {
    int sv = esrc[j];
    f16x4 vv = *(const f16x4*)&hbase[(size_t)sv * 256];
    float v = asrc[sv * 4 + h] + adn;
    v = (v > 0.f) ? v : 0.2f * v;
    float p = __expf(v);
    s += p;
#pragma unroll
    for (int k = 0; k < 4; ++k) acc[k] = fmaf(p, (float)vv[k], acc[k]);
  }
  float inv = 1.f / (s + 1e-16f);
  f16x4 ho;
#pragma unroll
  for (int k = 0; k < 4; ++k)
    ho[k] = (_Float16)fmaxf(fmaf(acc[k], inv, bias[lane * 4 + k]), 0.f);
  *(f16x4*)&outv[(size_t)node * 256 + lane * 4] = ho;
}

// ------------- layer-2 aggregation: one wave per node, 16 lanes per edge --------
__global__ __launch_bounds__(256) void agg2_kernel(const _Float16* __restrict__ hmat,
    const float* __restrict__ asrc, const float* __restrict__ adst,
    const int* __restrict__ offsets, const int* __restrict__ esrc,
    const float* __restrict__ bias, float* __restrict__ outv) {
  const int lane = threadIdx.x & 63, wid = threadIdx.x >> 6;
  const int node = blockIdx.x * 4 + wid;
  if (node >= NNODES) return;
  const int g = lane >> 4, q = lane & 15;
  const int start = offsets[node];
  const int deg = offsets[node + 1] - start;
  const float adn = adst[node];
  const _Float16* hbase = hmat + q * 4;
  float acc[4] = {0.f, 0.f, 0.f, 0.f};
  float s = 0.f;
  int jj = g;
  for (; jj + 4 < deg; jj += 8) {
    int sv0 = esrc[start + jj];
    int sv1 = esrc[start + jj + 4];
    f16x4 v0 = *(const f16x4*)&hbase[(size_t)sv0 * 64];
    f16x4 v1 = *(const f16x4*)&hbase[(size_t)sv1 * 64];
    float x0 = asrc[sv0] + adn;
    float x1 = asrc[sv1] + adn;
    x0 = (x0 > 0.f) ? x0 : 0.2f * x0;
    x1 = (x1 > 0.f) ? x1 : 0.2f * x1;
    float p0 = __expf(x0), p1 = __expf(x1);
    s += p0 + p1;
#pragma unroll
    for (int k = 0; k < 4; ++k) {
      acc[k] = fmaf(p0, (float)v0[k], acc[k]);
      acc[k] = fmaf(p1, (float)v1[k], acc[k]);
    }
  }
  for (; jj < deg; jj += 4) {
    int sv = esrc[start + jj];
    f16x4 v = *(const f16x4*)&hbase[(size_t)sv * 64];
    float x = asrc[sv] + adn;
    x = (x > 0.f) ? x : 0.2f * x;
    float p = __expf(x);
    s += p;
#pragma unroll
    for (int k = 0; k < 4; ++k) acc[k] = fmaf(p, (float)v[k], acc[k]);
  }
#pragma unroll
  for (int k = 0; k < 4; ++k) {
    acc[k] += __shfl_xor(acc[k], 16);
    acc[k] += __shfl_xor(acc[k], 32);
  }
  s += __shfl_xor(s, 16);
  s += __shfl_xor(s, 32);
  if (lane < 16) {
    float inv = 1.f / (s + 1e-16f);
    float4 o;
    o.x = fmaxf(fmaf(acc[0], inv, bias[q * 4 + 0]), 0.f);
    o.y = fmaxf(fmaf(acc[1], inv, bias[q * 4 + 1]), 0.f);
    o.z = fmaxf(fmaf(acc[2], inv, bias[q * 4 + 2]), 0.f);
    o.w = fmaxf(fmaf(acc[3], inv, bias[q * 4 + 3]), 0.f);
    *(float4*)&outv[(size_t)node * 64 + q * 4] = o;
  }
}

// ---------------- global mean pool ----------------
__global__ void graph_count_kernel(const int* __restrict__ batch, int* __restrict__ cnt, int n) {
  int g = threadIdx.x;
  if (g >= NGRAPH) return;
  int lo = 0, hi = n;
  while (lo < hi) { int mid = (lo + hi) >> 1; if (batch[mid] < g) lo = mid + 1; else hi = mid; }
  int lb = lo;
  hi = n;
  while (lo < hi) { int mid = (lo + hi) >> 1; if (batch[mid] < g + 1) lo = mid + 1; else hi = mid; }
  cnt[g] = lo - lb;
}

__global__ void pool_sum_kernel(const float* __restrict__ g2, const int* __restrict__ batch,
                                float* __restrict__ sums, int n) {
  int c = threadIdx.x;  // 64
  int beg = blockIdx.x * 64;
  int end = min(beg + 64, n);
  if (beg >= n) return;
  int cur = batch[beg];
  float acc = 0.f;
  for (int i = beg; i < end; ++i) {
    int g = batch[i];
    if (g != cur) {
      atomicAdd(&sums[cur * 64 + c], acc);
      acc = 0.f;
      cur = g;
    }
    acc += g2[(size_t)i * 64 + c];
  }
  atomicAdd(&sums[cur * 64 + c], acc);
}

__global__ void pool_div_kernel(const float* __restrict__ sums, const int* __restrict__ cnt,
                                float* __restrict__ out) {
  int i = blockIdx.x * blockDim.x + threadIdx.x;
  if (i < NGRAPH * 64) out[i] = sums[i] / fmaxf((float)cnt[i >> 6], 1.f);
}

// ---------------- launcher ----------------
extern "C" void kernel_launch(void* const* d_in, const int* in_sizes, int n_in,
                              void* d_out, int out_size, void* d_ws, size_t ws_size,
                              hipStream_t stream) {
  const float* x      = (const float*)d_in[0];
  const float* w1     = (const float*)d_in[1];
  const float* a_src1 = (const float*)d_in[2];
  const float* a_dst1 = (const float*)d_in[3];
  const float* b1     = (const float*)d_in[4];
  const float* w2     = (const float*)d_in[5];
  const float* a_src2 = (const float*)d_in[6];
  const float* a_dst2 = (const float*)d_in[7];
  const float* b2     = (const float*)d_in[8];
  const int*   src    = (const int*)d_in[9];
  const int*   dst    = src + NEDGES;
  const int*   batch  = (const int*)d_in[10];
  float* out = (float*)d_out;

  const int N = NNODES, E = NEDGES;
  const int NB = (N + 1023) / 1024;

  char* wsb = (char*)d_ws;
  size_t off = 0;
  auto alloc = [&](size_t bytes) {
    void* p = wsb + off;
    off = (off + bytes + 255) & ~(size_t)255;
    return p;
  };
  _Float16* h1h = (_Float16*)alloc((size_t)N * 256 * 2);
  _Float16* g1h = (_Float16*)alloc((size_t)N * 256 * 2);
  _Float16* h2h = (_Float16*)alloc((size_t)N * 64 * 2);
  float* g2     = (float*)alloc((size_t)N * 64 * 4);
  float* as1    = (float*)alloc((size_t)N * 4 * 4);
  float* ad1    = (float*)alloc((size_t)N * 4 * 4);
  float* as2    = (float*)alloc((size_t)N * 4);
  float* ad2    = (float*)alloc((size_t)N * 4);
  int* deg      = (int*)alloc((size_t)N * 4);
  int* inc      = (int*)alloc((size_t)N * 4);
  int* bsum     = (int*)alloc((size_t)NB * 4);
  int* boff     = (int*)alloc((size_t)NB * 4);
  int* offsets  = (int*)alloc((size_t)(N + 1) * 4);
  int* cursor   = (int*)alloc((size_t)N * 4);
  int* esrc     = (int*)alloc((size_t)E * 4);
  float* sums   = (float*)alloc((size_t)NGRAPH * 64 * 4);
  int* cnt      = (int*)alloc((size_t)NGRAPH * 4);

  // ---- CSR build ----
  hipMemsetAsync(deg, 0, (size_t)N * 4, stream);
  hist_kernel<<<(E + 255) / 256, 256, 0, stream>>>(dst, deg, E);
  scan1<<<NB, 1024, 0, stream>>>(deg, inc, bsum, N);
  scan2<<<1, 128, 0, stream>>>(bsum, boff, NB);
  scan3<<<(N + 255) / 256, 256, 0, stream>>>(inc, deg, boff, offsets, N, E);
  hipMemcpyAsync(cursor, offsets, (size_t)N * 4, hipMemcpyDeviceToDevice, stream);
  scatter_kernel<<<(E + 255) / 256, 256, 0, stream>>>(src, dst, cursor, esrc, E);

  // ---- layer 1 ----
  gemm_mfma<128, 256, float><<<(N + 127) / 128, 256, 0, stream>>>(x, w1, h1h, N);
  alpha_kernel<4><<<(N + 3) / 4, 256, 0, stream>>>(h1h, a_src1, a_dst1, as1, ad1, N);
  agg1_kernel<<<(N + 3) / 4, 256, 0, stream>>>(h1h, as1, ad1, offsets, esrc, b1, g1h);

  // ---- layer 2 ----
  gemm_mfma<256, 64, _Float16><<<(N + 127) / 128, 256, 0, stream>>>(g1h, w2, h2h, N);
  alpha_kernel<1><<<(N + 3) / 4, 256, 0, stream>>>(h2h, a_src2, a_dst2, as2, ad2, N);
  agg2_kernel<<<(N + 3) / 4, 256, 0, stream>>>(h2h, as2, ad2, offsets, esrc, b2, g2);

  // ---- pool ----
  hipMemsetAsync(sums, 0, (size_t)NGRAPH * 64 * 4, stream);
  graph_count_kernel<<<1, 128, 0, stream>>>(batch, cnt, N);
  pool_sum_kernel<<<(N + 63) / 64, 64, 0, stream>>>(g2, batch, sums, N);
  pool_div_kernel<<<(NGRAPH * 64 + 255) / 256, 256, 0, stream>>>(sums, cnt, out);
}

// Round 7
// 528.313 us; speedup vs baseline: 1.3042x; 1.1851x over previous
//
#include <hip/hip_runtime.h>
#include <math.h>
#include <type_traits>

#define NNODES 100000
#define NEDGES 1600000
#define NGRAPH 128

typedef _Float16 f16x4 __attribute__((ext_vector_type(4)));
typedef _Float16 f16x8 __attribute__((ext_vector_type(8)));
typedef float f32x4 __attribute__((ext_vector_type(4)));

// ---------------- MFMA GEMM: C[M,N] = A[M,K] * B[N,K]^T, BM=64, 2 blocks/CU ----
template <int K, int N, typename AT>
__global__ __launch_bounds__(256, 2) void gemm_mfma(const AT* __restrict__ A,
    const float* __restrict__ B, _Float16* __restrict__ C, int M) {
  constexpr int BM = 64;
  __shared__ _Float16 As[BM * K];
  __shared__ _Float16 Bs[N * K];
  const int tid = threadIdx.x;
  const int bm = blockIdx.x * BM;

  for (int i = tid * 4; i < BM * K; i += 1024) {
    int row = i / K;
    int k = i & (K - 1);
    int gr = bm + row;
    f16x4 h;
    if constexpr (std::is_same<AT, float>::value) {
      float4 v = {0.f, 0.f, 0.f, 0.f};
      if (gr < M) v = *(const float4*)&A[(size_t)gr * K + k];
      h[0] = (_Float16)v.x; h[1] = (_Float16)v.y; h[2] = (_Float16)v.z; h[3] = (_Float16)v.w;
    } else {
      f16x4 v = {};
      if (gr < M) v = *(const f16x4*)&A[(size_t)gr * K + k];
      h = v;
    }
    int idx = (row * K + k) ^ ((row & 7) << 3);
    *(f16x4*)&As[idx] = h;
  }
  for (int i = tid * 4; i < N * K; i += 1024) {
    int row = i / K;
    int k = i & (K - 1);
    float4 v = *(const float4*)&B[(size_t)row * K + k];
    f16x4 h;
    h[0] = (_Float16)v.x; h[1] = (_Float16)v.y; h[2] = (_Float16)v.z; h[3] = (_Float16)v.w;
    int idx = (row * K + k) ^ ((row & 7) << 3);
    *(f16x4*)&Bs[idx] = h;
  }
  __syncthreads();

  const int lane = tid & 63, wid = tid >> 6;
  const int lr = lane & 15;
  const int lk = (lane >> 4) * 8;
  constexpr int KS = K / 32, NT = N / 16;

  f16x8 a[KS];
#pragma unroll
  for (int ks = 0; ks < KS; ++ks) {
    int row = wid * 16 + lr;
    int idx = (row * K + ks * 32 + lk) ^ ((row & 7) << 3);
    a[ks] = *(const f16x8*)&As[idx];
  }

  f32x4 acc[NT];
#pragma unroll
  for (int nt = 0; nt < NT; ++nt) acc[nt] = (f32x4){0.f, 0.f, 0.f, 0.f};

#pragma unroll
  for (int nt = 0; nt < NT; ++nt)
#pragma unroll
    for (int ks = 0; ks < KS; ++ks) {
      int row = nt * 16 + lr;
      int idx = (row * K + ks * 32 + lk) ^ ((row & 7) << 3);
      f16x8 b = *(const f16x8*)&Bs[idx];
      acc[nt] = __builtin_amdgcn_mfma_f32_16x16x32_f16(a[ks], b, acc[nt], 0, 0, 0);
    }

  int row0 = bm + wid * 16 + (lane >> 4) * 4;
#pragma unroll
  for (int nt = 0; nt < NT; ++nt)
#pragma unroll
    for (int r = 0; r < 4; ++r) {
      int row = row0 + r;
      if (row < M) C[(size_t)row * N + nt * 16 + lr] = (_Float16)acc[nt][r];
    }
}

// ---------------- attention logits, layer 1 (H=4): wave/node, coalesced row ----
__global__ void alpha1_kernel(const _Float16* __restrict__ hmat,
                              const float* __restrict__ a_src, const float* __restrict__ a_dst,
                              float* __restrict__ asrc, float* __restrict__ adst, int n) {
  const int lane = threadIdx.x & 63;
  const int node = blockIdx.x * 4 + (threadIdx.x >> 6);
  if (node >= n) return;
  const int q = lane & 15, h = lane >> 4;
  f16x4 v4 = *(const f16x4*)&hmat[(size_t)node * 256 + lane * 4];
  float vs = 0.f, vd = 0.f;
#pragma unroll
  for (int k = 0; k < 4; ++k) {
    float v = (float)v4[k];
    vs = fmaf(v, a_src[lane * 4 + k], vs);
    vd = fmaf(v, a_dst[lane * 4 + k], vd);
  }
#pragma unroll
  for (int o = 1; o < 16; o <<= 1) {
    vs += __shfl_xor(vs, o);
    vd += __shfl_xor(vd, o);
  }
  if (q == 0) { asrc[node * 4 + h] = vs; adst[node * 4 + h] = vd; }
}

// ---------------- attention logits, layer 2 (H=1): 16 lanes/node --------------
__global__ void alpha2_kernel(const _Float16* __restrict__ hmat,
                              const float* __restrict__ a_src, const float* __restrict__ a_dst,
                              float* __restrict__ asrc, float* __restrict__ adst, int n) {
  const int tid = threadIdx.x;
  const int node = blockIdx.x * 16 + (tid >> 4);
  if (node >= n) return;
  const int q = tid & 15;
  f16x4 v4 = *(const f16x4*)&hmat[(size_t)node * 64 + q * 4];
  float vs = 0.f, vd = 0.f;
#pragma unroll
  for (int k = 0; k < 4; ++k) {
    float v = (float)v4[k];
    vs = fmaf(v, a_src[q * 4 + k], vs);
    vd = fmaf(v, a_dst[q * 4 + k], vd);
  }
#pragma unroll
  for (int o = 1; o < 16; o <<= 1) {
    vs += __shfl_xor(vs, o);
    vd += __shfl_xor(vd, o);
  }
  if (q == 0) { asrc[node] = vs; adst[node] = vd; }
}

// ---------------- CSR build ----------------
__global__ void hist_kernel(const int* __restrict__ dstv, int* __restrict__ deg, int e_count) {
  int e = blockIdx.x * blockDim.x + threadIdx.x;
  if (e < e_count) atomicAdd(&deg[dstv[e]], 1);
}

__global__ __launch_bounds__(1024) void scan1(const int* __restrict__ deg, int* __restrict__ inc,
                                              int* __restrict__ bsum, int n) {
  __shared__ int sm[1024];
  int i = blockIdx.x * 1024 + threadIdx.x;
  sm[threadIdx.x] = (i < n) ? deg[i] : 0;
  __syncthreads();
  for (int o = 1; o < 1024; o <<= 1) {
    int t = (threadIdx.x >= o) ? sm[threadIdx.x - o] : 0;
    __syncthreads();
    sm[threadIdx.x] += t;
    __syncthreads();
  }
  if (i < n) inc[i] = sm[threadIdx.x];
  if (threadIdx.x == 1023) bsum[blockIdx.x] = sm[1023];
}

__global__ void scan2(const int* __restrict__ bsum, int* __restrict__ boff, int nb) {
  __shared__ int sm[128];
  int t = threadIdx.x;
  int own = (t < nb) ? bsum[t] : 0;
  sm[t] = own;
  __syncthreads();
  for (int o = 1; o < 128; o <<= 1) {
    int u = (t >= o) ? sm[t - o] : 0;
    __syncthreads();
    sm[t] += u;
    __syncthreads();
  }
  if (t < nb) boff[t] = sm[t] - own;
}

__global__ void scan3(const int* __restrict__ inc, const int* __restrict__ deg,
                      const int* __restrict__ boff, int* __restrict__ offsets,
                      int* __restrict__ cursor, int n, int e_count) {
  int i = blockIdx.x * blockDim.x + threadIdx.x;
  if (i < n) {
    int v = inc[i] - deg[i] + boff[i >> 10];
    offsets[i] = v;
    cursor[i] = v;
  }
  if (i == 0) offsets[n] = e_count;
}

__global__ void scatter_kernel(const int* __restrict__ srcv, const int* __restrict__ dstv,
                               int* __restrict__ cursor, int* __restrict__ esrc, int e_count) {
  int e = blockIdx.x * blockDim.x + threadIdx.x;
  if (e < e_count) {
    int p = atomicAdd(&cursor[dstv[e]], 1);
    esrc[p] = srcv[e];
  }
}

// ------------- layer-1 aggregation: one WAVE per node, no LDS, no barriers ------
__global__ __launch_bounds__(256) void agg1_kernel(const _Float16* __restrict__ hmat,
    const float* __restrict__ asrc, const float* __restrict__ adst,
    const int* __restrict__ offsets, const int* __restrict__ esrc,
    const float* __restrict__ bias, _Float16* __restrict__ outv) {
  const int lane = threadIdx.x & 63, wid = threadIdx.x >> 6;
  const int node = blockIdx.x * 4 + wid;
  if (node >= NNODES) return;
  const int h = lane >> 4;
  const int start = offsets[node];
  const int end = offsets[node + 1];
  const float adn = adst[node * 4 + h];
  const _Float16* hbase = hmat + lane * 4;
  float acc[4] = {0.f, 0.f, 0.f, 0.f};
  float s = 0.f;
  int j = start;
  for (; j + 8 <= end; j += 8) {
    int sv[8];
#pragma unroll
    for (int t = 0; t < 8; ++t) sv[t] = esrc[j + t];
    f16x4 vv[8];
#pragma unroll
    for (int t = 0; t < 8; ++t) vv[t] = *(const f16x4*)&hbase[(size_t)sv[t] * 256];
    _Float16 ph[8];
#pragma unroll
    for (int t = 0; t < 8; ++t) {
      float v = asrc[sv[t] * 4 + h] + adn;
      v = (v > 0.f) ? v : 0.2f * v;
      float p = __expf(v);
      s += p;
      ph[t] = (_Float16)p;
    }
#pragma unroll
    for (int t = 0; t < 8; ++t)
#pragma unroll
      for (int k = 0; k < 4; ++k)
        acc[k] = fmaf((float)vv[t][k], (float)ph[t], acc[k]);  // v_fma_mix_f32
  }
  for (; j < end; ++j) {
    int sv = esrc[j];
    f16x4 vv = *(const f16x4*)&hbase[(size_t)sv * 256];
    float v = asrc[sv * 4 + h] + adn;
    v = (v > 0.f) ? v : 0.2f * v;
    float p = __expf(v);
    s += p;
    _Float16 phs = (_Float16)p;
#pragma unroll
    for (int k = 0; k < 4; ++k) acc[k] = fmaf((float)vv[k], (float)phs, acc[k]);
  }
  float inv = 1.f / (s + 1e-16f);
  f16x4 ho;
#pragma unroll
  for (int k = 0; k < 4; ++k)
    ho[k] = (_Float16)fmaxf(fmaf(acc[k], inv, bias[lane * 4 + k]), 0.f);
  *(f16x4*)&outv[(size_t)node * 256 + lane * 4] = ho;
}

// ------------- layer-2 aggregation: one wave per node, 16 lanes per edge --------
__global__ __launch_bounds__(256) void agg2_kernel(const _Float16* __restrict__ hmat,
    const float* __restrict__ asrc, const float* __restrict__ adst,
    const int* __restrict__ offsets, const int* __restrict__ esrc,
    const float* __restrict__ bias, float* __restrict__ outv) {
  const int lane = threadIdx.x & 63, wid = threadIdx.x >> 6;
  const int node = blockIdx.x * 4 + wid;
  if (node >= NNODES) return;
  const int g = lane >> 4, q = lane & 15;
  const int start = offsets[node];
  const int deg = offsets[node + 1] - start;
  const float adn = adst[node];
  const _Float16* hbase = hmat + q * 4;
  float acc[4] = {0.f, 0.f, 0.f, 0.f};
  float s = 0.f;
  int jj = g;
  for (; jj + 4 < deg; jj += 8) {
    int sv0 = esrc[start + jj];
    int sv1 = esrc[start + jj + 4];
    f16x4 v0 = *(const f16x4*)&hbase[(size_t)sv0 * 64];
    f16x4 v1 = *(const f16x4*)&hbase[(size_t)sv1 * 64];
    float x0 = asrc[sv0] + adn;
    float x1 = asrc[sv1] + adn;
    x0 = (x0 > 0.f) ? x0 : 0.2f * x0;
    x1 = (x1 > 0.f) ? x1 : 0.2f * x1;
    float p0 = __expf(x0), p1 = __expf(x1);
    s += p0 + p1;
    _Float16 ph0 = (_Float16)p0, ph1 = (_Float16)p1;
#pragma unroll
    for (int k = 0; k < 4; ++k) {
      acc[k] = fmaf((float)v0[k], (float)ph0, acc[k]);
      acc[k] = fmaf((float)v1[k], (float)ph1, acc[k]);
    }
  }
  for (; jj < deg; jj += 4) {
    int sv = esrc[start + jj];
    f16x4 v = *(const f16x4*)&hbase[(size_t)sv * 64];
    float x = asrc[sv] + adn;
    x = (x > 0.f) ? x : 0.2f * x;
    float p = __expf(x);
    s += p;
    _Float16 phs = (_Float16)p;
#pragma unroll
    for (int k = 0; k < 4; ++k) acc[k] = fmaf((float)v[k], (float)phs, acc[k]);
  }
#pragma unroll
  for (int k = 0; k < 4; ++k) {
    acc[k] += __shfl_xor(acc[k], 16);
    acc[k] += __shfl_xor(acc[k], 32);
  }
  s += __shfl_xor(s, 16);
  s += __shfl_xor(s, 32);
  if (lane < 16) {
    float inv = 1.f / (s + 1e-16f);
    float4 o;
    o.x = fmaxf(fmaf(acc[0], inv, bias[q * 4 + 0]), 0.f);
    o.y = fmaxf(fmaf(acc[1], inv, bias[q * 4 + 1]), 0.f);
    o.z = fmaxf(fmaf(acc[2], inv, bias[q * 4 + 2]), 0.f);
    o.w = fmaxf(fmaf(acc[3], inv, bias[q * 4 + 3]), 0.f);
    *(float4*)&outv[(size_t)node * 64 + q * 4] = o;
  }
}

// ---------------- global mean pool ----------------
__global__ void pool_sum_kernel(const float* __restrict__ g2, const int* __restrict__ batch,
                                float* __restrict__ sums, int n) {
  int c = threadIdx.x;  // 64
  int beg = blockIdx.x * 64;
  int end = min(beg + 64, n);
  if (beg >= n) return;
  int cur = batch[beg];
  float acc = 0.f;
  for (int i = beg; i < end; ++i) {
    int g = batch[i];
    if (g != cur) {
      atomicAdd(&sums[cur * 64 + c], acc);
      acc = 0.f;
      cur = g;
    }
    acc += g2[(size_t)i * 64 + c];
  }
  atomicAdd(&sums[cur * 64 + c], acc);
}

// one block per graph; inline binary-search count (batch sorted)
__global__ void pool_div_kernel(const float* __restrict__ sums, const int* __restrict__ batch,
                                float* __restrict__ out, int n) {
  int g = blockIdx.x;
  int c = threadIdx.x;
  int lo = 0, hi = n;
  while (lo < hi) { int mid = (lo + hi) >> 1; if (batch[mid] < g) lo = mid + 1; else hi = mid; }
  int lb = lo;
  hi = n;
  while (lo < hi) { int mid = (lo + hi) >> 1; if (batch[mid] < g + 1) lo = mid + 1; else hi = mid; }
  float cnt = fmaxf((float)(lo - lb), 1.f);
  out[g * 64 + c] = sums[g * 64 + c] / cnt;
}

// ---------------- launcher ----------------
extern "C" void kernel_launch(void* const* d_in, const int* in_sizes, int n_in,
                              void* d_out, int out_size, void* d_ws, size_t ws_size,
                              hipStream_t stream) {
  const float* x      = (const float*)d_in[0];
  const float* w1     = (const float*)d_in[1];
  const float* a_src1 = (const float*)d_in[2];
  const float* a_dst1 = (const float*)d_in[3];
  const float* b1     = (const float*)d_in[4];
  const float* w2     = (const float*)d_in[5];
  const float* a_src2 = (const float*)d_in[6];
  const float* a_dst2 = (const float*)d_in[7];
  const float* b2     = (const float*)d_in[8];
  const int*   src    = (const int*)d_in[9];
  const int*   dst    = src + NEDGES;
  const int*   batch  = (const int*)d_in[10];
  float* out = (float*)d_out;

  const int N = NNODES, E = NEDGES;
  const int NB = (N + 1023) / 1024;

  char* wsb = (char*)d_ws;
  size_t off = 0;
  auto alloc = [&](size_t bytes) {
    void* p = wsb + off;
    off = (off + bytes + 255) & ~(size_t)255;
    return p;
  };
  _Float16* h1h = (_Float16*)alloc((size_t)N * 256 * 2);
  _Float16* g1h = (_Float16*)alloc((size_t)N * 256 * 2);
  _Float16* h2h = (_Float16*)alloc((size_t)N * 64 * 2);
  float* g2     = (float*)alloc((size_t)N * 64 * 4);
  float* as1    = (float*)alloc((size_t)N * 4 * 4);
  float* ad1    = (float*)alloc((size_t)N * 4 * 4);
  float* as2    = (float*)alloc((size_t)N * 4);
  float* ad2    = (float*)alloc((size_t)N * 4);
  int* deg      = (int*)alloc((size_t)N * 4);
  int* inc      = (int*)alloc((size_t)N * 4);
  int* bsum     = (int*)alloc((size_t)NB * 4);
  int* boff     = (int*)alloc((size_t)NB * 4);
  int* offsets  = (int*)alloc((size_t)(N + 1) * 4);
  int* cursor   = (int*)alloc((size_t)N * 4);
  int* esrc     = (int*)alloc((size_t)E * 4);
  float* sums   = (float*)alloc((size_t)NGRAPH * 64 * 4);

  // ---- CSR build ----
  hipMemsetAsync(deg, 0, (size_t)N * 4, stream);
  hist_kernel<<<(E + 255) / 256, 256, 0, stream>>>(dst, deg, E);
  scan1<<<NB, 1024, 0, stream>>>(deg, inc, bsum, N);
  scan2<<<1, 128, 0, stream>>>(bsum, boff, NB);
  scan3<<<(N + 255) / 256, 256, 0, stream>>>(inc, deg, boff, offsets, cursor, N, E);
  scatter_kernel<<<(E + 255) / 256, 256, 0, stream>>>(src, dst, cursor, esrc, E);

  // ---- layer 1 ----
  gemm_mfma<128, 256, float><<<(N + 63) / 64, 256, 0, stream>>>(x, w1, h1h, N);
  alpha1_kernel<<<(N + 3) / 4, 256, 0, stream>>>(h1h, a_src1, a_dst1, as1, ad1, N);
  agg1_kernel<<<(N + 3) / 4, 256, 0, stream>>>(h1h, as1, ad1, offsets, esrc, b1, g1h);

  // ---- layer 2 ----
  gemm_mfma<256, 64, _Float16><<<(N + 63) / 64, 256, 0, stream>>>(g1h, w2, h2h, N);
  alpha2_kernel<<<(N + 15) / 16, 256, 0, stream>>>(h2h, a_src2, a_dst2, as2, ad2, N);
  agg2_kernel<<<(N + 3) / 4, 256, 0, stream>>>(h2h, as2, ad2, offsets, esrc, b2, g2);

  // ---- pool ----
  hipMemsetAsync(sums, 0, (size_t)NGRAPH * 64 * 4, stream);
  pool_sum_kernel<<<(N + 63) / 64, 64, 0, stream>>>(g2, batch, sums, N);
  pool_div_kernel<<<NGRAPH, 64, 0, stream>>>(sums, batch, out, N);
}

// Round 8
// 515.711 us; speedup vs baseline: 1.3361x; 1.0244x over previous
//
#include <hip/hip_runtime.h>
#include <math.h>
#include <type_traits>

#define NNODES 100000
#define NEDGES 1600000
#define NGRAPH 128

typedef _Float16 f16x4 __attribute__((ext_vector_type(4)));
typedef _Float16 f16x8 __attribute__((ext_vector_type(8)));
typedef float f32x4 __attribute__((ext_vector_type(4)));

// ------- MFMA GEMM + fused attention-logit epilogue -------
// C[M,N] = A[M,K]*B[N,K]^T; also asrc[i,h]=sum_c C[i,c]*a_src[c] (per 64-ch head),
// adst likewise. H = N/64 heads.
template <int K, int N, typename AT>
__global__ __launch_bounds__(256, 2) void gemm_mfma(const AT* __restrict__ A,
    const float* __restrict__ B, _Float16* __restrict__ C, int M,
    const float* __restrict__ a_src, const float* __restrict__ a_dst,
    float* __restrict__ asrc, float* __restrict__ adst) {
  constexpr int BM = 64;
  constexpr int H = N / 64;
  __shared__ _Float16 As[BM * K];
  __shared__ _Float16 Bs[N * K];
  const int tid = threadIdx.x;
  const int bm = blockIdx.x * BM;

  for (int i = tid * 4; i < BM * K; i += 1024) {
    int row = i / K;
    int k = i & (K - 1);
    int gr = bm + row;
    f16x4 h;
    if constexpr (std::is_same<AT, float>::value) {
      float4 v = {0.f, 0.f, 0.f, 0.f};
      if (gr < M) v = *(const float4*)&A[(size_t)gr * K + k];
      h[0] = (_Float16)v.x; h[1] = (_Float16)v.y; h[2] = (_Float16)v.z; h[3] = (_Float16)v.w;
    } else {
      f16x4 v = {};
      if (gr < M) v = *(const f16x4*)&A[(size_t)gr * K + k];
      h = v;
    }
    int idx = (row * K + k) ^ ((row & 7) << 3);
    *(f16x4*)&As[idx] = h;
  }
  for (int i = tid * 4; i < N * K; i += 1024) {
    int row = i / K;
    int k = i & (K - 1);
    float4 v = *(const float4*)&B[(size_t)row * K + k];
    f16x4 h;
    h[0] = (_Float16)v.x; h[1] = (_Float16)v.y; h[2] = (_Float16)v.z; h[3] = (_Float16)v.w;
    int idx = (row * K + k) ^ ((row & 7) << 3);
    *(f16x4*)&Bs[idx] = h;
  }
  __syncthreads();

  const int lane = tid & 63, wid = tid >> 6;
  const int lr = lane & 15;
  const int lk = (lane >> 4) * 8;
  constexpr int KS = K / 32, NT = N / 16;

  f16x8 a[KS];
#pragma unroll
  for (int ks = 0; ks < KS; ++ks) {
    int row = wid * 16 + lr;
    int idx = (row * K + ks * 32 + lk) ^ ((row & 7) << 3);
    a[ks] = *(const f16x8*)&As[idx];
  }

  f32x4 acc[NT];
#pragma unroll
  for (int nt = 0; nt < NT; ++nt) acc[nt] = (f32x4){0.f, 0.f, 0.f, 0.f};

#pragma unroll
  for (int nt = 0; nt < NT; ++nt)
#pragma unroll
    for (int ks = 0; ks < KS; ++ks) {
      int row = nt * 16 + lr;
      int idx = (row * K + ks * 32 + lk) ^ ((row & 7) << 3);
      f16x8 b = *(const f16x8*)&Bs[idx];
      acc[nt] = __builtin_amdgcn_mfma_f32_16x16x32_f16(a[ks], b, acc[nt], 0, 0, 0);
    }

  // a_src/a_dst coefficients for this lane's column samples
  float cs[NT], cd[NT];
#pragma unroll
  for (int nt = 0; nt < NT; ++nt) {
    cs[nt] = a_src[nt * 16 + lr];
    cd[nt] = a_dst[nt * 16 + lr];
  }

  int row0 = bm + wid * 16 + (lane >> 4) * 4;
#pragma unroll
  for (int r = 0; r < 4; ++r) {
    int row = row0 + r;
    float ps[H], pd[H];
#pragma unroll
    for (int h = 0; h < H; ++h) { ps[h] = 0.f; pd[h] = 0.f; }
#pragma unroll
    for (int nt = 0; nt < NT; ++nt) {
      int h = nt >> 2;
      if (H == 1) h = 0;
      ps[h] = fmaf(acc[nt][r], cs[nt], ps[h]);
      pd[h] = fmaf(acc[nt][r], cd[nt], pd[h]);
    }
#pragma unroll
    for (int o = 1; o < 16; o <<= 1) {
#pragma unroll
      for (int h = 0; h < H; ++h) {
        ps[h] += __shfl_xor(ps[h], o);
        pd[h] += __shfl_xor(pd[h], o);
      }
    }
    if (row < M) {
#pragma unroll
      for (int nt = 0; nt < NT; ++nt) C[(size_t)row * N + nt * 16 + lr] = (_Float16)acc[nt][r];
      if (lr == 0) {
        if (H == 4) {
          *(float4*)&asrc[row * 4] = make_float4(ps[0], ps[1], ps[2], ps[3 % H]);
          *(float4*)&adst[row * 4] = make_float4(pd[0], pd[1], pd[2], pd[3 % H]);
        } else {
          asrc[row] = ps[0];
          adst[row] = pd[0];
        }
      }
    }
  }
}

// ---------------- CSR build ----------------
__global__ void hist_kernel(const int* __restrict__ dstv, int* __restrict__ deg, int e_count) {
  int e = blockIdx.x * blockDim.x + threadIdx.x;
  if (e < e_count) atomicAdd(&deg[dstv[e]], 1);
}

__global__ __launch_bounds__(1024) void scan1(const int* __restrict__ deg, int* __restrict__ inc,
                                              int* __restrict__ bsum, int n) {
  __shared__ int sm[1024];
  int i = blockIdx.x * 1024 + threadIdx.x;
  sm[threadIdx.x] = (i < n) ? deg[i] : 0;
  __syncthreads();
  for (int o = 1; o < 1024; o <<= 1) {
    int t = (threadIdx.x >= o) ? sm[threadIdx.x - o] : 0;
    __syncthreads();
    sm[threadIdx.x] += t;
    __syncthreads();
  }
  if (i < n) inc[i] = sm[threadIdx.x];
  if (threadIdx.x == 1023) bsum[blockIdx.x] = sm[1023];
}

__global__ void scan2(const int* __restrict__ bsum, int* __restrict__ boff, int nb) {
  __shared__ int sm[128];
  int t = threadIdx.x;
  int own = (t < nb) ? bsum[t] : 0;
  sm[t] = own;
  __syncthreads();
  for (int o = 1; o < 128; o <<= 1) {
    int u = (t >= o) ? sm[t - o] : 0;
    __syncthreads();
    sm[t] += u;
    __syncthreads();
  }
  if (t < nb) boff[t] = sm[t] - own;
}

__global__ void scan3(const int* __restrict__ inc, const int* __restrict__ deg,
                      const int* __restrict__ boff, int* __restrict__ offsets,
                      int* __restrict__ cursor, int n, int e_count) {
  int i = blockIdx.x * blockDim.x + threadIdx.x;
  if (i < n) {
    int v = inc[i] - deg[i] + boff[i >> 10];
    offsets[i] = v;
    cursor[i] = v;
  }
  if (i == 0) offsets[n] = e_count;
}

__global__ void scatter_kernel(const int* __restrict__ srcv, const int* __restrict__ dstv,
                               int* __restrict__ cursor, int* __restrict__ esrc, int e_count) {
  int e = blockIdx.x * blockDim.x + threadIdx.x;
  if (e < e_count) {
    int p = atomicAdd(&cursor[dstv[e]], 1);
    esrc[p] = srcv[e];
  }
}

// ------------- layer-1 aggregation: one WAVE per node, 12-deep gather pipeline --
__global__ __launch_bounds__(256) void agg1_kernel(const _Float16* __restrict__ hmat,
    const float* __restrict__ asrc, const float* __restrict__ adst,
    const int* __restrict__ offsets, const int* __restrict__ esrc,
    const float* __restrict__ bias, _Float16* __restrict__ outv) {
  const int lane = threadIdx.x & 63, wid = threadIdx.x >> 6;
  const int node = blockIdx.x * 4 + wid;
  if (node >= NNODES) return;
  const int h = lane >> 4;
  const int start = offsets[node];
  const int end = offsets[node + 1];
  const float adn = adst[node * 4 + h];
  const _Float16* hbase = hmat + lane * 4;
  float acc[4] = {0.f, 0.f, 0.f, 0.f};
  float s = 0.f;
  int j = start;
  for (; j + 12 <= end; j += 12) {
    int sv[12];
#pragma unroll
    for (int t = 0; t < 12; ++t) sv[t] = esrc[j + t];
    f16x4 vv[12];
#pragma unroll
    for (int t = 0; t < 12; ++t) vv[t] = *(const f16x4*)&hbase[(size_t)sv[t] * 256];
    _Float16 ph[12];
#pragma unroll
    for (int t = 0; t < 12; ++t) {
      float v = asrc[sv[t] * 4 + h] + adn;
      v = (v > 0.f) ? v : 0.2f * v;
      float p = __expf(v);
      s += p;
      ph[t] = (_Float16)p;
    }
#pragma unroll
    for (int t = 0; t < 12; ++t)
#pragma unroll
      for (int k = 0; k < 4; ++k)
        acc[k] = fmaf((float)vv[t][k], (float)ph[t], acc[k]);  // v_fma_mix_f32
  }
  for (; j + 4 <= end; j += 4) {
    int sv[4];
#pragma unroll
    for (int t = 0; t < 4; ++t) sv[t] = esrc[j + t];
    f16x4 vv[4];
#pragma unroll
    for (int t = 0; t < 4; ++t) vv[t] = *(const f16x4*)&hbase[(size_t)sv[t] * 256];
#pragma unroll
    for (int t = 0; t < 4; ++t) {
      float v = asrc[sv[t] * 4 + h] + adn;
      v = (v > 0.f) ? v : 0.2f * v;
      float p = __expf(v);
      s += p;
      _Float16 phs = (_Float16)p;
#pragma unroll
      for (int k = 0; k < 4; ++k) acc[k] = fmaf((float)vv[t][k], (float)phs, acc[k]);
    }
  }
  for (; j < end; ++j) {
    int sv = esrc[j];
    f16x4 vv = *(const f16x4*)&hbase[(size_t)sv * 256];
    float v = asrc[sv * 4 + h] + adn;
    v = (v > 0.f) ? v : 0.2f * v;
    float p = __expf(v);
    s += p;
    _Float16 phs = (_Float16)p;
#pragma unroll
    for (int k = 0; k < 4; ++k) acc[k] = fmaf((float)vv[k], (float)phs, acc[k]);
  }
  float inv = 1.f / (s + 1e-16f);
  f16x4 ho;
#pragma unroll
  for (int k = 0; k < 4; ++k)
    ho[k] = (_Float16)fmaxf(fmaf(acc[k], inv, bias[lane * 4 + k]), 0.f);
  *(f16x4*)&outv[(size_t)node * 256 + lane * 4] = ho;
}

// ------------- layer-2 aggregation: 16 lanes/edge, 4 rows in flight per group ---
__global__ __launch_bounds__(256) void agg2_kernel(const _Float16* __restrict__ hmat,
    const float* __restrict__ asrc, const float* __restrict__ adst,
    const int* __restrict__ offsets, const int* __restrict__ esrc,
    const float* __restrict__ bias, float* __restrict__ outv) {
  const int lane = threadIdx.x & 63, wid = threadIdx.x >> 6;
  const int node = blockIdx.x * 4 + wid;
  if (node >= NNODES) return;
  const int g = lane >> 4, q = lane & 15;
  const int start = offsets[node];
  const int deg = offsets[node + 1] - start;
  const float adn = adst[node];
  const _Float16* hbase = hmat + q * 4;
  float acc[4] = {0.f, 0.f, 0.f, 0.f};
  float s = 0.f;
  int jj = g;
  for (; jj + 12 < deg; jj += 16) {
    int sv[4];
#pragma unroll
    for (int t = 0; t < 4; ++t) sv[t] = esrc[start + jj + t * 4];
    f16x4 v[4];
#pragma unroll
    for (int t = 0; t < 4; ++t) v[t] = *(const f16x4*)&hbase[(size_t)sv[t] * 64];
#pragma unroll
    for (int t = 0; t < 4; ++t) {
      float x = asrc[sv[t]] + adn;
      x = (x > 0.f) ? x : 0.2f * x;
      float p = __expf(x);
      s += p;
      _Float16 phs = (_Float16)p;
#pragma unroll
      for (int k = 0; k < 4; ++k) acc[k] = fmaf((float)v[t][k], (float)phs, acc[k]);
    }
  }
  for (; jj < deg; jj += 4) {
    int sv = esrc[start + jj];
    f16x4 v = *(const f16x4*)&hbase[(size_t)sv * 64];
    float x = asrc[sv] + adn;
    x = (x > 0.f) ? x : 0.2f * x;
    float p = __expf(x);
    s += p;
    _Float16 phs = (_Float16)p;
#pragma unroll
    for (int k = 0; k < 4; ++k) acc[k] = fmaf((float)v[k], (float)phs, acc[k]);
  }
#pragma unroll
  for (int k = 0; k < 4; ++k) {
    acc[k] += __shfl_xor(acc[k], 16);
    acc[k] += __shfl_xor(acc[k], 32);
  }
  s += __shfl_xor(s, 16);
  s += __shfl_xor(s, 32);
  if (lane < 16) {
    float inv = 1.f / (s + 1e-16f);
    float4 o;
    o.x = fmaxf(fmaf(acc[0], inv, bias[q * 4 + 0]), 0.f);
    o.y = fmaxf(fmaf(acc[1], inv, bias[q * 4 + 1]), 0.f);
    o.z = fmaxf(fmaf(acc[2], inv, bias[q * 4 + 2]), 0.f);
    o.w = fmaxf(fmaf(acc[3], inv, bias[q * 4 + 3]), 0.f);
    *(float4*)&outv[(size_t)node * 64 + q * 4] = o;
  }
}

// ---------------- global mean pool ----------------
__global__ void pool_sum_kernel(const float* __restrict__ g2, const int* __restrict__ batch,
                                float* __restrict__ sums, int n) {
  int c = threadIdx.x;  // 64
  int beg = blockIdx.x * 64;
  int end = min(beg + 64, n);
  if (beg >= n) return;
  int cur = batch[beg];
  float acc = 0.f;
  for (int i = beg; i < end; ++i) {
    int g = batch[i];
    if (g != cur) {
      atomicAdd(&sums[cur * 64 + c], acc);
      acc = 0.f;
      cur = g;
    }
    acc += g2[(size_t)i * 64 + c];
  }
  atomicAdd(&sums[cur * 64 + c], acc);
}

__global__ void pool_div_kernel(const float* __restrict__ sums, const int* __restrict__ batch,
                                float* __restrict__ out, int n) {
  int g = blockIdx.x;
  int c = threadIdx.x;
  int lo = 0, hi = n;
  while (lo < hi) { int mid = (lo + hi) >> 1; if (batch[mid] < g) lo = mid + 1; else hi = mid; }
  int lb = lo;
  hi = n;
  while (lo < hi) { int mid = (lo + hi) >> 1; if (batch[mid] < g + 1) lo = mid + 1; else hi = mid; }
  float cnt = fmaxf((float)(lo - lb), 1.f);
  out[g * 64 + c] = sums[g * 64 + c] / cnt;
}

// ---------------- launcher ----------------
extern "C" void kernel_launch(void* const* d_in, const int* in_sizes, int n_in,
                              void* d_out, int out_size, void* d_ws, size_t ws_size,
                              hipStream_t stream) {
  const float* x      = (const float*)d_in[0];
  const float* w1     = (const float*)d_in[1];
  const float* a_src1 = (const float*)d_in[2];
  const float* a_dst1 = (const float*)d_in[3];
  const float* b1     = (const float*)d_in[4];
  const float* w2     = (const float*)d_in[5];
  const float* a_src2 = (const float*)d_in[6];
  const float* a_dst2 = (const float*)d_in[7];
  const float* b2     = (const float*)d_in[8];
  const int*   src    = (const int*)d_in[9];
  const int*   dst    = src + NEDGES;
  const int*   batch  = (const int*)d_in[10];
  float* out = (float*)d_out;

  const int N = NNODES, E = NEDGES;
  const int NB = (N + 1023) / 1024;

  char* wsb = (char*)d_ws;
  size_t off = 0;
  auto alloc = [&](size_t bytes) {
    void* p = wsb + off;
    off = (off + bytes + 255) & ~(size_t)255;
    return p;
  };
  _Float16* h1h = (_Float16*)alloc((size_t)N * 256 * 2);
  _Float16* g1h = (_Float16*)alloc((size_t)N * 256 * 2);
  _Float16* h2h = (_Float16*)alloc((size_t)N * 64 * 2);
  float* g2     = (float*)alloc((size_t)N * 64 * 4);
  float* as1    = (float*)alloc((size_t)N * 4 * 4);
  float* ad1    = (float*)alloc((size_t)N * 4 * 4);
  float* as2    = (float*)alloc((size_t)N * 4);
  float* ad2    = (float*)alloc((size_t)N * 4);
  int* deg      = (int*)alloc((size_t)N * 4);
  int* inc      = (int*)alloc((size_t)N * 4);
  int* bsum     = (int*)alloc((size_t)NB * 4);
  int* boff     = (int*)alloc((size_t)NB * 4);
  int* offsets  = (int*)alloc((size_t)(N + 1) * 4);
  int* cursor   = (int*)alloc((size_t)N * 4);
  int* esrc     = (int*)alloc((size_t)E * 4);
  float* sums   = (float*)alloc((size_t)NGRAPH * 64 * 4);

  // ---- CSR build ----
  hipMemsetAsync(deg, 0, (size_t)N * 4, stream);
  hist_kernel<<<(E + 255) / 256, 256, 0, stream>>>(dst, deg, E);
  scan1<<<NB, 1024, 0, stream>>>(deg, inc, bsum, N);
  scan2<<<1, 128, 0, stream>>>(bsum, boff, NB);
  scan3<<<(N + 255) / 256, 256, 0, stream>>>(inc, deg, boff, offsets, cursor, N, E);
  scatter_kernel<<<(E + 255) / 256, 256, 0, stream>>>(src, dst, cursor, esrc, E);

  // ---- layer 1 ----
  gemm_mfma<128, 256, float><<<(N + 63) / 64, 256, 0, stream>>>(
      x, w1, h1h, N, a_src1, a_dst1, as1, ad1);
  agg1_kernel<<<(N + 3) / 4, 256, 0, stream>>>(h1h, as1, ad1, offsets, esrc, b1, g1h);

  // ---- layer 2 ----
  gemm_mfma<256, 64, _Float16><<<(N + 63) / 64, 256, 0, stream>>>(
      g1h, w2, h2h, N, a_src2, a_dst2, as2, ad2);
  agg2_kernel<<<(N + 3) / 4, 256, 0, stream>>>(h2h, as2, ad2, offsets, esrc, b2, g2);

  // ---- pool ----
  hipMemsetAsync(sums, 0, (size_t)NGRAPH * 64 * 4, stream);
  pool_sum_kernel<<<(N + 63) / 64, 64, 0, stream>>>(g2, batch, sums, N);
  pool_div_kernel<<<NGRAPH, 64, 0, stream>>>(sums, batch, out, N);
}